// Round 4
// baseline (211.635 us; speedup 1.0000x reference)
//
#include <hip/hip_runtime.h>

typedef __bf16 bf16_t;
typedef __bf16 bf16x8 __attribute__((ext_vector_type(8)));
typedef __bf16 bf16x4 __attribute__((ext_vector_type(4)));
typedef float f32x4 __attribute__((ext_vector_type(4)));
typedef float f32x16 __attribute__((ext_vector_type(16)));

#if __has_builtin(__builtin_amdgcn_exp2f)
#define EXP2F __builtin_amdgcn_exp2f
#else
#define EXP2F exp2f
#endif

// ---------------- constants (problem shape is fixed) ----------------
#define BATCH 2
#define SEQ   2048
#define DIM   1024
#define NQH   16
#define NKVH  4
#define HD    64
#define ROWS  (BATCH*SEQ)      // 4096
#define QKVN  1536             // 1024 q + 256 k + 256 v
#define QSCALE 0.1803368801111f   // 0.125 * log2(e), folded into Q at projection

// async global->LDS DMA, 16B per lane, LDS dest = wave-uniform base + lane*16
static __device__ __forceinline__ void gld16(const bf16_t* g, bf16_t* l) {
    __builtin_amdgcn_global_load_lds((const __attribute__((address_space(1))) void*)g,
                                     (__attribute__((address_space(3))) void*)l,
                                     16, 0, 0);
}

// ======================= cast x -> bf16 =======================
__global__ __launch_bounds__(256) void cast_x_kernel(const float* __restrict__ x,
                                                     bf16_t* __restrict__ o) {
    size_t i = ((size_t)blockIdx.x * 256 + threadIdx.x) * 4;
    float4 v = *(const float4*)(x + i);
    bf16x4 r;
    r[0] = (bf16_t)v.x; r[1] = (bf16_t)v.y; r[2] = (bf16_t)v.z; r[3] = (bf16_t)v.w;
    *(bf16x4*)(o + i) = r;
}

// ============ all 4 weight transposes in ONE dispatch ============
__global__ __launch_bounds__(256) void transpose_w_all(const float* __restrict__ wq,
                                                       const float* __restrict__ wk,
                                                       const float* __restrict__ wv,
                                                       const float* __restrict__ wo,
                                                       bf16_t* __restrict__ WqkvT,
                                                       bf16_t* __restrict__ WoT) {
    int bid = blockIdx.x;          // 0..639
    const float* src; bf16_t* dst; int N, nt, kt2;
    if (bid < 256)      { src = wq; dst = WqkvT;                      N = 1024; int i = bid;       nt = i & 15; kt2 = i >> 4; }
    else if (bid < 320) { src = wk; dst = WqkvT + (size_t)1024*1024;  N = 256;  int i = bid - 256; nt = i & 3;  kt2 = i >> 2; }
    else if (bid < 384) { src = wv; dst = WqkvT + (size_t)1280*1024;  N = 256;  int i = bid - 320; nt = i & 3;  kt2 = i >> 2; }
    else                { src = wo; dst = WoT;                        N = 1024; int i = bid - 384; nt = i & 15; kt2 = i >> 4; }

    __shared__ float tile[64][65];
    int t = threadIdx.x;
    {
        int r = t >> 2, cb = (t & 3) * 16;
        const float* s = src + (size_t)(kt2 * 64 + r) * N + nt * 64 + cb;
#pragma unroll
        for (int j = 0; j < 16; j += 4) {
            float4 v = *(const float4*)(s + j);
            tile[r][cb + j + 0] = v.x; tile[r][cb + j + 1] = v.y;
            tile[r][cb + j + 2] = v.z; tile[r][cb + j + 3] = v.w;
        }
    }
    __syncthreads();
    {
        int n = t >> 2, kb = (t & 3) * 16;
        union { bf16_t h[16]; uint4 u[2]; } pk;
#pragma unroll
        for (int j = 0; j < 16; ++j) pk.h[j] = (bf16_t)tile[kb + j][n];
        bf16_t* d = dst + (size_t)(nt * 64 + n) * 1024 + kt2 * 64 + kb;
        ((uint4*)d)[0] = pk.u[0];
        ((uint4*)d)[1] = pk.u[1];
    }
}

// ======================= GEMM1: x @ Wqkv^T with fused RoPE + layout epilogue =======================
// K layout out: Kb[b][kv][kt][d>>3][key&63][d&7]   (tile-contiguous, 4096 elem/tile)
// V layout out: Vt[b][kv][kt][key>>3 (local)][d][key&7] (tile-contiguous)
__global__ __launch_bounds__(256, 2) void gemm_qkv_kernel(const bf16_t* __restrict__ A,
                                                          const bf16_t* __restrict__ Bt,
                                                          const float* __restrict__ fcos,
                                                          const float* __restrict__ fsin,
                                                          bf16_t* __restrict__ Qb,
                                                          bf16_t* __restrict__ Kb,
                                                          bf16_t* __restrict__ Vt) {
    const int K = 1024;
    __shared__ __align__(16) bf16_t As[128 * 32];
    __shared__ __align__(16) bf16_t Bs[128 * 32];
    int t = threadIdx.x;
    int w = t >> 6, L = t & 63, quad = L >> 4, l15 = L & 15;
    int wr = (w >> 1) * 64, wc = (w & 1) * 64;
    int bnb = blockIdx.x;                 // 0..11
    int bn = bnb * 128, bm = blockIdx.y * 128;

    const bf16_t* Ag0 = A  + (size_t)(bm + w * 32 + (L >> 2)) * K + (L & 3) * 8;
    const bf16_t* Ag1 = Ag0 + (size_t)16 * K;
    const bf16_t* Bg0 = Bt + (size_t)(bn + w * 32 + (L >> 2)) * K + (L & 3) * 8;
    const bf16_t* Bg1 = Bg0 + (size_t)16 * K;
    bf16_t* Al = As + w * 1024;
    bf16_t* Bl = Bs + w * 1024;

    f32x4 acc[4][4] = {};

    for (int k0 = 0; k0 < K; k0 += 32) {
        __syncthreads();
        gld16(Ag0 + k0, Al);
        gld16(Ag1 + k0, Al + 512);
        gld16(Bg0 + k0, Bl);
        gld16(Bg1 + k0, Bl + 512);
        __syncthreads();

        bf16x8 a[4], b[4];
#pragma unroll
        for (int i = 0; i < 4; ++i) {
            a[i] = ((const bf16x8*)As)[(wr + 16 * i + l15) * 4 + quad];
            b[i] = ((const bf16x8*)Bs)[(wc + 16 * i + l15) * 4 + quad];
        }
#pragma unroll
        for (int i = 0; i < 4; ++i)
#pragma unroll
            for (int j = 0; j < 4; ++j)
                acc[i][j] = __builtin_amdgcn_mfma_f32_16x16x32_bf16(a[i], b[j], acc[i][j], 0, 0, 0);
    }

    // ---- fused epilogue ----
    int region = (bnb >= 10) ? 2 : (bnb >= 8) ? 1 : 0;
#pragma unroll
    for (int i = 0; i < 4; ++i) {
        int row0 = bm + wr + 16 * i + quad * 4;
        int b = row0 >> 11, s0 = row0 & 2047;
#pragma unroll
        for (int j = 0; j < 4; ++j) {
            int col = bn + wc + 16 * j + l15;
            if (region == 2) {                      // V: tile-contiguous permuted layout
                int kvh = (col >> 6) - 20, d = col & 63;
                int kt = s0 >> 6, kl = s0 & 63;
                bf16x4 o;
#pragma unroll
                for (int r = 0; r < 4; ++r) o[r] = (bf16_t)acc[i][j][r];
                *(bf16x4*)(Vt + ((size_t)((b * NKVH + kvh) * 32 + kt)) * 4096
                              + ((kl >> 3) * 64 + d) * 8 + (kl & 7)) = o;
            } else {                                // Q or K: RoPE
                int d = col & 63, fi = d >> 1;
                int odd = col & 1;
#pragma unroll
                for (int r = 0; r < 4; ++r) {
                    int s = s0 + r;
                    float v = acc[i][j][r];
                    float p = __shfl_xor(v, 1);
                    float c = fcos[s * 32 + fi], sn = fsin[s * 32 + fi];
                    float o = odd ? (p * sn + v * c) : (v * c - p * sn);
                    if (region == 0) {
                        int h = col >> 6;
                        Qb[((size_t)((b * NQH + h) * SEQ + s)) * HD + d] = (bf16_t)(o * QSCALE);
                    } else {                        // K: tile-contiguous [d>>3][key][d&7]
                        int kvh = (col >> 6) - 16;
                        int kt = s >> 6, kl = s & 63;
                        Kb[((size_t)((b * NKVH + kvh) * 32 + kt)) * 4096
                           + ((d >> 3) * 64 + kl) * 8 + (d & 7)] = (bf16_t)o;
                    }
                }
            }
        }
    }
}

// ======================= GEMM2: attn @ Wo^T, fp32 out =======================
__global__ __launch_bounds__(256, 2) void gemm_bt_kernel(const bf16_t* __restrict__ A,
                                                         const bf16_t* __restrict__ Bt,
                                                         float* __restrict__ C,
                                                         int M, int N, int K) {
    __shared__ __align__(16) bf16_t As[128 * 32];
    __shared__ __align__(16) bf16_t Bs[128 * 32];
    int t = threadIdx.x;
    int w = t >> 6, L = t & 63, quad = L >> 4, l15 = L & 15;
    int wr = (w >> 1) * 64, wc = (w & 1) * 64;
    int bn = blockIdx.x * 128, bm = blockIdx.y * 128;

    const bf16_t* Ag0 = A  + (size_t)(bm + w * 32 + (L >> 2)) * K + (L & 3) * 8;
    const bf16_t* Ag1 = Ag0 + (size_t)16 * K;
    const bf16_t* Bg0 = Bt + (size_t)(bn + w * 32 + (L >> 2)) * K + (L & 3) * 8;
    const bf16_t* Bg1 = Bg0 + (size_t)16 * K;
    bf16_t* Al = As + w * 1024;
    bf16_t* Bl = Bs + w * 1024;

    f32x4 acc[4][4] = {};

    for (int k0 = 0; k0 < K; k0 += 32) {
        __syncthreads();
        gld16(Ag0 + k0, Al);
        gld16(Ag1 + k0, Al + 512);
        gld16(Bg0 + k0, Bl);
        gld16(Bg1 + k0, Bl + 512);
        __syncthreads();

        bf16x8 a[4], b[4];
#pragma unroll
        for (int i = 0; i < 4; ++i) {
            a[i] = ((const bf16x8*)As)[(wr + 16 * i + l15) * 4 + quad];
            b[i] = ((const bf16x8*)Bs)[(wc + 16 * i + l15) * 4 + quad];
        }
#pragma unroll
        for (int i = 0; i < 4; ++i)
#pragma unroll
            for (int j = 0; j < 4; ++j)
                acc[i][j] = __builtin_amdgcn_mfma_f32_16x16x32_bf16(a[i], b[j], acc[i][j], 0, 0, 0);
    }

#pragma unroll
    for (int i = 0; i < 4; ++i) {
        int row = bm + wr + 16 * i + quad * 4;
#pragma unroll
        for (int j = 0; j < 4; ++j) {
            int col = bn + wc + 16 * j + l15;
            float* cp = C + (size_t)row * N + col;
#pragma unroll
            for (int r = 0; r < 4; ++r)
                cp[(size_t)r * N] = acc[i][j][r];
        }
    }
}

// ======================= flash attention v4: 32x32x16 MFMA, causal, GQA 4:1 =======================
// S^T = K·Q^T per wave over 32 q-rows (A-frag m=key=kg*32+l31, k=d=16ks+8hi+j).
// C-layout (32x32): col=q=l31, row=key=(reg&3)+8(reg>>2)+4hi+32kg.
// P -> PV B-frag (B[k=key=16t+8hi+j][n=q=l31]) via 2 shfl_xor(32) per k-slice.
// O^T = V^T·P^T. Block = 8 waves: wave-group 0 handles qt=bq, group 1 qt=15-bq,
// both concurrently sharing one K/V staging stream (iters = 32-2*bq, uniform-ish).
// Ks LDS: [d>>3][key][8]; Vs LDS: [keyl>>3][d][8] -- both conflict-free b128 reads,
// both staged linearly from tile-contiguous global layouts via gld16.
__global__ __launch_bounds__(512) void attn_kernel(const bf16_t* __restrict__ Qb,
                                                   const bf16_t* __restrict__ Kb,
                                                   const bf16_t* __restrict__ Vt,
                                                   bf16_t* __restrict__ Ob) {
    int bq = blockIdx.x, h = blockIdx.y, b = blockIdx.z;
    int kv = h >> 2;
    int t = threadIdx.x, w = t >> 6, lane = t & 63, hi = lane >> 5, l31 = lane & 31;
    int wg = w & 3;
    int qt = (w >> 2) == 0 ? bq : (15 - bq);
    int wq0 = qt * 128 + wg * 32;
    int q = wq0 + l31;
    int myktmax = (wq0 + 31) >> 6;                 // inclusive; single partial (diag) tile
    int ktmax_blk = 31 - 2 * bq;                   // = (max(bq,15-bq)*128+127)>>6

    __shared__ __align__(16) bf16_t Ks2[4096];     // 8 KB
    __shared__ __align__(16) bf16_t Vs2[4096];     // 8 KB

    const bf16_t* Ktile = Kb + ((size_t)((b * NKVH + kv) * 32)) * 4096;
    const bf16_t* Vtile = Vt + ((size_t)((b * NKVH + kv) * 32)) * 4096;
    const bf16_t* Qrow  = Qb + ((size_t)((b * NQH + h) * SEQ + q)) * HD;

    // Q fragments: B[n=q=l31][k=d=16ks+8hi+j]
    bf16x8 qf[4];
#pragma unroll
    for (int ks = 0; ks < 4; ++ks)
        qf[ks] = *(const bf16x8*)(Qrow + ks * 16 + hi * 8);

    f32x16 acc[2] = {};      // O^T: d-tiles dg=0,1
    float rs = 0.f;

    for (int kt = 0; kt <= ktmax_blk; ++kt) {
        __syncthreads();
        gld16(Ktile + (size_t)kt * 4096 + t * 8, Ks2 + w * 512);
        gld16(Vtile + (size_t)kt * 4096 + t * 8, Vs2 + w * 512);
        __syncthreads();
        if (kt > myktmax) continue;                // wave-uniform; barriers stay matched

        // ---- S^T: 2 key-groups x 4 d-slices ----
        f32x16 st[2];
#pragma unroll
        for (int kg = 0; kg < 2; ++kg) {
            f32x16 z = {};
#pragma unroll
            for (int ks = 0; ks < 4; ++ks) {
                bf16x8 ak = *(const bf16x8*)(Ks2 + ((ks * 2 + hi) * 64 + kg * 32 + l31) * 8);
                z = __builtin_amdgcn_mfma_f32_32x32x16_bf16(ak, qf[ks], z, 0, 0, 0);
            }
            st[kg] = z;
        }

        // ---- P = exp2(S^T) (+ diagonal mask), pack into bf16x4 groups ----
        bool diag = (kt == myktmax);
        uint2 pk[2][2][2];
#pragma unroll
        for (int c = 0; c < 2; ++c)
#pragma unroll
            for (int u = 0; u < 2; ++u)
#pragma unroll
                for (int hh = 0; hh < 2; ++hh) {
                    bf16x4 g;
#pragma unroll
                    for (int jl = 0; jl < 4; ++jl) {
                        int r = 8 * u + 4 * hh + jl;
                        float p = EXP2F(st[c][r]);
                        if (diag) {
                            int key = kt * 64 + 32 * c + 16 * u + 8 * hh + 4 * hi + jl;
                            if (key > q) p = 0.f;
                        }
                        rs += p;
                        g[jl] = (bf16_t)p;
                    }
                    union { bf16x4 b4; uint2 u2; } cv; cv.b4 = g;
                    pk[c][u][hh] = cv.u2;
                }

        // ---- O^T += V^T · P^T : 4 key-slices x 2 d-groups ----
#pragma unroll
        for (int tt = 0; tt < 4; ++tt) {
            int u = tt & 1, c = tt >> 1;
            uint2 keep = hi ? pk[c][u][1] : pk[c][u][0];
            uint2 send = hi ? pk[c][u][0] : pk[c][u][1];
            uint2 recv;
            recv.x = __shfl_xor(send.x, 32);
            recv.y = __shfl_xor(send.y, 32);
            union { uint4 u4; bf16x8 b8; } fr;
            fr.u4 = hi ? make_uint4(recv.x, recv.y, keep.x, keep.y)
                       : make_uint4(keep.x, keep.y, recv.x, recv.y);
#pragma unroll
            for (int dg = 0; dg < 2; ++dg) {
                bf16x8 av = *(const bf16x8*)(Vs2 + ((tt * 2 + hi) * 64 + dg * 32 + l31) * 8);
                acc[dg] = __builtin_amdgcn_mfma_f32_32x32x16_bf16(av, fr.b8, acc[dg], 0, 0, 0);
            }
        }
    }

    // ---- epilogue: O^T/l -> Ob[b][q][h*64+d] ----
    rs += __shfl_xor(rs, 32);
    float rinv = 1.0f / rs;
    bf16_t* obase = Ob + (size_t)(b * SEQ + q) * DIM + h * HD;
#pragma unroll
    for (int dg = 0; dg < 2; ++dg)
#pragma unroll
        for (int g2 = 0; g2 < 4; ++g2) {
            bf16x4 o;
#pragma unroll
            for (int jl = 0; jl < 4; ++jl) o[jl] = (bf16_t)(acc[dg][4 * g2 + jl] * rinv);
            *(bf16x4*)(obase + 32 * dg + 8 * g2 + 4 * hi) = o;
        }
}

// ======================= launcher =======================
extern "C" void kernel_launch(void* const* d_in, const int* in_sizes, int n_in,
                              void* d_out, int out_size, void* d_ws, size_t ws_size,
                              hipStream_t stream) {
    const float* x    = (const float*)d_in[0];
    const float* fcos = (const float*)d_in[2];
    const float* fsin = (const float*)d_in[3];
    const float* wq   = (const float*)d_in[5];
    const float* wk   = (const float*)d_in[6];
    const float* wv   = (const float*)d_in[7];
    const float* wo   = (const float*)d_in[8];
    float* out = (float*)d_out;

    char* ws = (char*)d_ws;
    bf16_t* Xb    = (bf16_t*)(ws + 0);            //  8 MB  [4096][1024]
    bf16_t* Attnb = Xb;                           // alias (Xb dead after gemm_qkv)
    bf16_t* WqkvT = (bf16_t*)(ws + 8388608);      //  3 MB  [1536][1024]
    bf16_t* WoT   = (bf16_t*)(ws + 11534336);     //  2 MB  [1024][1024]
    bf16_t* Qb    = (bf16_t*)(ws + 13631488);     //  8 MB  [B][16][S][64]
    bf16_t* Kb    = (bf16_t*)(ws + 22020096);     //  2 MB  [B][4][32 tiles][4096]
    bf16_t* Vt    = (bf16_t*)(ws + 24117248);     //  2 MB  [B][4][32 tiles][4096]
    // total 26,214,400 B

    cast_x_kernel<<<ROWS * DIM / 1024, 256, 0, stream>>>(x, Xb);
    transpose_w_all<<<640, 256, 0, stream>>>(wq, wk, wv, wo, WqkvT, WoT);

    gemm_qkv_kernel<<<dim3(QKVN / 128, ROWS / 128), 256, 0, stream>>>(Xb, WqkvT, fcos, fsin, Qb, Kb, Vt);

    attn_kernel<<<dim3(8, NQH, BATCH), 512, 0, stream>>>(Qb, Kb, Vt, Attnb);

    gemm_bt_kernel<<<dim3(DIM / 128, ROWS / 128), 256, 0, stream>>>(Attnb, WoT, out, ROWS, DIM, DIM);
}

// Round 5
// 207.769 us; speedup vs baseline: 1.0186x; 1.0186x over previous
//
#include <hip/hip_runtime.h>

typedef __bf16 bf16_t;
typedef __bf16 bf16x8 __attribute__((ext_vector_type(8)));
typedef __bf16 bf16x4 __attribute__((ext_vector_type(4)));
typedef float f32x4 __attribute__((ext_vector_type(4)));
typedef float f32x16 __attribute__((ext_vector_type(16)));

#if __has_builtin(__builtin_amdgcn_exp2f)
#define EXP2F __builtin_amdgcn_exp2f
#else
#define EXP2F exp2f
#endif

// ---------------- constants (problem shape is fixed) ----------------
#define BATCH 2
#define SEQ   2048
#define DIM   1024
#define NQH   16
#define NKVH  4
#define HD    64
#define ROWS  (BATCH*SEQ)      // 4096
#define QKVN  1536             // 1024 q + 256 k + 256 v
#define QSCALE 0.1803368801111f   // 0.125 * log2(e), folded into Q at projection

// async global->LDS DMA, 16B per lane, LDS dest = wave-uniform base + lane*16
static __device__ __forceinline__ void gld16(const bf16_t* g, bf16_t* l) {
    __builtin_amdgcn_global_load_lds((const __attribute__((address_space(1))) void*)g,
                                     (__attribute__((address_space(3))) void*)l,
                                     16, 0, 0);
}

// ======================= cast x -> bf16 =======================
__global__ __launch_bounds__(256) void cast_x_kernel(const float* __restrict__ x,
                                                     bf16_t* __restrict__ o) {
    size_t i = ((size_t)blockIdx.x * 256 + threadIdx.x) * 4;
    float4 v = *(const float4*)(x + i);
    bf16x4 r;
    r[0] = (bf16_t)v.x; r[1] = (bf16_t)v.y; r[2] = (bf16_t)v.z; r[3] = (bf16_t)v.w;
    *(bf16x4*)(o + i) = r;
}

// ============ all 4 weight transposes in ONE dispatch ============
__global__ __launch_bounds__(256) void transpose_w_all(const float* __restrict__ wq,
                                                       const float* __restrict__ wk,
                                                       const float* __restrict__ wv,
                                                       const float* __restrict__ wo,
                                                       bf16_t* __restrict__ WqkvT,
                                                       bf16_t* __restrict__ WoT) {
    int bid = blockIdx.x;          // 0..639
    const float* src; bf16_t* dst; int N, nt, kt2;
    if (bid < 256)      { src = wq; dst = WqkvT;                      N = 1024; int i = bid;       nt = i & 15; kt2 = i >> 4; }
    else if (bid < 320) { src = wk; dst = WqkvT + (size_t)1024*1024;  N = 256;  int i = bid - 256; nt = i & 3;  kt2 = i >> 2; }
    else if (bid < 384) { src = wv; dst = WqkvT + (size_t)1280*1024;  N = 256;  int i = bid - 320; nt = i & 3;  kt2 = i >> 2; }
    else                { src = wo; dst = WoT;                        N = 1024; int i = bid - 384; nt = i & 15; kt2 = i >> 4; }

    __shared__ float tile[64][65];
    int t = threadIdx.x;
    {
        int r = t >> 2, cb = (t & 3) * 16;
        const float* s = src + (size_t)(kt2 * 64 + r) * N + nt * 64 + cb;
#pragma unroll
        for (int j = 0; j < 16; j += 4) {
            float4 v = *(const float4*)(s + j);
            tile[r][cb + j + 0] = v.x; tile[r][cb + j + 1] = v.y;
            tile[r][cb + j + 2] = v.z; tile[r][cb + j + 3] = v.w;
        }
    }
    __syncthreads();
    {
        int n = t >> 2, kb = (t & 3) * 16;
        union { bf16_t h[16]; uint4 u[2]; } pk;
#pragma unroll
        for (int j = 0; j < 16; ++j) pk.h[j] = (bf16_t)tile[kb + j][n];
        bf16_t* d = dst + (size_t)(nt * 64 + n) * 1024 + kt2 * 64 + kb;
        ((uint4*)d)[0] = pk.u[0];
        ((uint4*)d)[1] = pk.u[1];
    }
}

// ======================= GEMM1: x @ Wqkv^T with fused RoPE + layout epilogue =======================
// K layout out: Kb[b][kv][kt][d>>3][key&63][d&7]   (tile-contiguous, 4096 elem/tile)
// V layout out: Vt[b][kv][kt][key>>3 (local)][d][key&7] (tile-contiguous)
__global__ __launch_bounds__(256, 2) void gemm_qkv_kernel(const bf16_t* __restrict__ A,
                                                          const bf16_t* __restrict__ Bt,
                                                          const float* __restrict__ fcos,
                                                          const float* __restrict__ fsin,
                                                          bf16_t* __restrict__ Qb,
                                                          bf16_t* __restrict__ Kb,
                                                          bf16_t* __restrict__ Vt) {
    const int K = 1024;
    __shared__ __align__(16) bf16_t As[128 * 32];
    __shared__ __align__(16) bf16_t Bs[128 * 32];
    int t = threadIdx.x;
    int w = t >> 6, L = t & 63, quad = L >> 4, l15 = L & 15;
    int wr = (w >> 1) * 64, wc = (w & 1) * 64;
    int bnb = blockIdx.x;                 // 0..11
    int bn = bnb * 128, bm = blockIdx.y * 128;

    const bf16_t* Ag0 = A  + (size_t)(bm + w * 32 + (L >> 2)) * K + (L & 3) * 8;
    const bf16_t* Ag1 = Ag0 + (size_t)16 * K;
    const bf16_t* Bg0 = Bt + (size_t)(bn + w * 32 + (L >> 2)) * K + (L & 3) * 8;
    const bf16_t* Bg1 = Bg0 + (size_t)16 * K;
    bf16_t* Al = As + w * 1024;
    bf16_t* Bl = Bs + w * 1024;

    f32x4 acc[4][4] = {};

    for (int k0 = 0; k0 < K; k0 += 32) {
        __syncthreads();
        gld16(Ag0 + k0, Al);
        gld16(Ag1 + k0, Al + 512);
        gld16(Bg0 + k0, Bl);
        gld16(Bg1 + k0, Bl + 512);
        __syncthreads();

        bf16x8 a[4], b[4];
#pragma unroll
        for (int i = 0; i < 4; ++i) {
            a[i] = ((const bf16x8*)As)[(wr + 16 * i + l15) * 4 + quad];
            b[i] = ((const bf16x8*)Bs)[(wc + 16 * i + l15) * 4 + quad];
        }
#pragma unroll
        for (int i = 0; i < 4; ++i)
#pragma unroll
            for (int j = 0; j < 4; ++j)
                acc[i][j] = __builtin_amdgcn_mfma_f32_16x16x32_bf16(a[i], b[j], acc[i][j], 0, 0, 0);
    }

    // ---- fused epilogue ----
    int region = (bnb >= 10) ? 2 : (bnb >= 8) ? 1 : 0;
#pragma unroll
    for (int i = 0; i < 4; ++i) {
        int row0 = bm + wr + 16 * i + quad * 4;
        int b = row0 >> 11, s0 = row0 & 2047;
#pragma unroll
        for (int j = 0; j < 4; ++j) {
            int col = bn + wc + 16 * j + l15;
            if (region == 2) {                      // V: tile-contiguous permuted layout
                int kvh = (col >> 6) - 20, d = col & 63;
                int kt = s0 >> 6, kl = s0 & 63;
                bf16x4 o;
#pragma unroll
                for (int r = 0; r < 4; ++r) o[r] = (bf16_t)acc[i][j][r];
                *(bf16x4*)(Vt + ((size_t)((b * NKVH + kvh) * 32 + kt)) * 4096
                              + ((kl >> 3) * 64 + d) * 8 + (kl & 7)) = o;
            } else {                                // Q or K: RoPE
                int d = col & 63, fi = d >> 1;
                int odd = col & 1;
#pragma unroll
                for (int r = 0; r < 4; ++r) {
                    int s = s0 + r;
                    float v = acc[i][j][r];
                    float p = __shfl_xor(v, 1);
                    float c = fcos[s * 32 + fi], sn = fsin[s * 32 + fi];
                    float o = odd ? (p * sn + v * c) : (v * c - p * sn);
                    if (region == 0) {
                        int h = col >> 6;
                        Qb[((size_t)((b * NQH + h) * SEQ + s)) * HD + d] = (bf16_t)(o * QSCALE);
                    } else {                        // K: tile-contiguous [d>>3][key][d&7]
                        int kvh = (col >> 6) - 16;
                        int kt = s >> 6, kl = s & 63;
                        Kb[((size_t)((b * NKVH + kvh) * 32 + kt)) * 4096
                           + ((d >> 3) * 64 + kl) * 8 + (d & 7)] = (bf16_t)o;
                    }
                }
            }
        }
    }
}

// ======================= GEMM2: attn @ Wo^T, fp32 out =======================
__global__ __launch_bounds__(256, 2) void gemm_bt_kernel(const bf16_t* __restrict__ A,
                                                         const bf16_t* __restrict__ Bt,
                                                         float* __restrict__ C,
                                                         int M, int N, int K) {
    __shared__ __align__(16) bf16_t As[128 * 32];
    __shared__ __align__(16) bf16_t Bs[128 * 32];
    int t = threadIdx.x;
    int w = t >> 6, L = t & 63, quad = L >> 4, l15 = L & 15;
    int wr = (w >> 1) * 64, wc = (w & 1) * 64;
    int bn = blockIdx.x * 128, bm = blockIdx.y * 128;

    const bf16_t* Ag0 = A  + (size_t)(bm + w * 32 + (L >> 2)) * K + (L & 3) * 8;
    const bf16_t* Ag1 = Ag0 + (size_t)16 * K;
    const bf16_t* Bg0 = Bt + (size_t)(bn + w * 32 + (L >> 2)) * K + (L & 3) * 8;
    const bf16_t* Bg1 = Bg0 + (size_t)16 * K;
    bf16_t* Al = As + w * 1024;
    bf16_t* Bl = Bs + w * 1024;

    f32x4 acc[4][4] = {};

    for (int k0 = 0; k0 < K; k0 += 32) {
        __syncthreads();
        gld16(Ag0 + k0, Al);
        gld16(Ag1 + k0, Al + 512);
        gld16(Bg0 + k0, Bl);
        gld16(Bg1 + k0, Bl + 512);
        __syncthreads();

        bf16x8 a[4], b[4];
#pragma unroll
        for (int i = 0; i < 4; ++i) {
            a[i] = ((const bf16x8*)As)[(wr + 16 * i + l15) * 4 + quad];
            b[i] = ((const bf16x8*)Bs)[(wc + 16 * i + l15) * 4 + quad];
        }
#pragma unroll
        for (int i = 0; i < 4; ++i)
#pragma unroll
            for (int j = 0; j < 4; ++j)
                acc[i][j] = __builtin_amdgcn_mfma_f32_16x16x32_bf16(a[i], b[j], acc[i][j], 0, 0, 0);
    }

#pragma unroll
    for (int i = 0; i < 4; ++i) {
        int row = bm + wr + 16 * i + quad * 4;
#pragma unroll
        for (int j = 0; j < 4; ++j) {
            int col = bn + wc + 16 * j + l15;
            float* cp = C + (size_t)row * N + col;
#pragma unroll
            for (int r = 0; r < 4; ++r)
                cp[(size_t)r * N] = acc[i][j][r];
        }
    }
}

// ======================= flash attention v5: 32x32x16 MFMA, causal, GQA 4:1 =======================
// Same verified math/layout as v4; new schedule:
//  - 256-thread blocks (4 waves x 32 q-rows = one 128-row q-tile)
//  - 512 blocks; block u and u+256 carry complementary q-tiles (qt, 15-qt) of the
//    SAME head -> with round-robin dispatch each CU gets 2 independent barrier
//    domains, combined load exactly 34 key-tiles, overlapping K/V streams.
//  - register prefetch of next K/V tile (4x uint4/thread), proven in r2/r3.
__global__ __launch_bounds__(256, 2) void attn_kernel(const bf16_t* __restrict__ Qb,
                                                      const bf16_t* __restrict__ Kb,
                                                      const bf16_t* __restrict__ Vt,
                                                      bf16_t* __restrict__ Ob) {
    int u = blockIdx.x;
    int half = u >> 8, v5 = u & 255;
    int qt8 = v5 >> 5, b = (v5 >> 4) & 1, h = v5 & 15;
    int qt = half ? (15 - qt8) : qt8;
    int kv = h >> 2;
    int t = threadIdx.x, w = t >> 6, lane = t & 63, hi = lane >> 5, l31 = lane & 31;
    int q = qt * 128 + w * 32 + l31;
    int myktmax = (qt * 128 + w * 32 + 31) >> 6;   // 2qt (w<2) or 2qt+1 (w>=2)
    int ktmax = 2 * qt + 1;                        // block-wide inclusive

    __shared__ __align__(16) bf16_t Ks2[4096];     // 8 KB  [d>>3][key][8]
    __shared__ __align__(16) bf16_t Vs2[4096];     // 8 KB  [keyl>>3][d][8]

    const uint4* Kt4 = (const uint4*)(Kb + ((size_t)((b * NKVH + kv) * 32)) * 4096);
    const uint4* Vt4 = (const uint4*)(Vt + ((size_t)((b * NKVH + kv) * 32)) * 4096);
    const bf16_t* Qrow = Qb + ((size_t)((b * NQH + h) * SEQ + q)) * HD;

    // Q fragments: B[n=q=l31][k=d=16ks+8hi+j]
    bf16x8 qf[4];
#pragma unroll
    for (int ks = 0; ks < 4; ++ks)
        qf[ks] = *(const bf16x8*)(Qrow + ks * 16 + hi * 8);

    f32x16 acc[2] = {};      // O^T: d-tiles dg=0,1
    float rs = 0.f;

    // register prefetch: thread t owns uint4 chunks {t, t+256} of each 512-chunk tile
    uint4 kp0 = Kt4[t], kp1 = Kt4[t + 256];
    uint4 vp0 = Vt4[t], vp1 = Vt4[t + 256];

    for (int kt = 0; kt <= ktmax; ++kt) {
        __syncthreads();
        ((uint4*)Ks2)[t] = kp0; ((uint4*)Ks2)[t + 256] = kp1;
        ((uint4*)Vs2)[t] = vp0; ((uint4*)Vs2)[t + 256] = vp1;
        __syncthreads();
        if (kt < ktmax) {
            int o = (kt + 1) * 512 + t;
            kp0 = Kt4[o]; kp1 = Kt4[o + 256];
            vp0 = Vt4[o]; vp1 = Vt4[o + 256];
        }
        if (kt > myktmax) continue;                // wave-uniform; barriers stay matched

        // ---- S^T: 2 key-groups x 4 d-slices ----
        f32x16 st[2];
#pragma unroll
        for (int kg = 0; kg < 2; ++kg) {
            f32x16 z = {};
#pragma unroll
            for (int ks = 0; ks < 4; ++ks) {
                bf16x8 ak = *(const bf16x8*)(Ks2 + ((ks * 2 + hi) * 64 + kg * 32 + l31) * 8);
                z = __builtin_amdgcn_mfma_f32_32x32x16_bf16(ak, qf[ks], z, 0, 0, 0);
            }
            st[kg] = z;
        }

        // ---- P = exp2(S^T) (+ diagonal mask), pack into bf16x4 groups ----
        bool diag = (kt == myktmax);
        uint2 pk[2][2][2];
#pragma unroll
        for (int c = 0; c < 2; ++c)
#pragma unroll
            for (int uu = 0; uu < 2; ++uu)
#pragma unroll
                for (int hh = 0; hh < 2; ++hh) {
                    bf16x4 g;
#pragma unroll
                    for (int jl = 0; jl < 4; ++jl) {
                        int r = 8 * uu + 4 * hh + jl;
                        float p = EXP2F(st[c][r]);
                        if (diag) {
                            int key = kt * 64 + 32 * c + 16 * uu + 8 * hh + 4 * hi + jl;
                            if (key > q) p = 0.f;
                        }
                        rs += p;
                        g[jl] = (bf16_t)p;
                    }
                    union { bf16x4 b4; uint2 u2; } cv; cv.b4 = g;
                    pk[c][uu][hh] = cv.u2;
                }

        // ---- O^T += V^T · P^T : 4 key-slices x 2 d-groups ----
#pragma unroll
        for (int tt = 0; tt < 4; ++tt) {
            int uu = tt & 1, c = tt >> 1;
            uint2 keep = hi ? pk[c][uu][1] : pk[c][uu][0];
            uint2 send = hi ? pk[c][uu][0] : pk[c][uu][1];
            uint2 recv;
            recv.x = __shfl_xor(send.x, 32);
            recv.y = __shfl_xor(send.y, 32);
            union { uint4 u4; bf16x8 b8; } fr;
            fr.u4 = hi ? make_uint4(recv.x, recv.y, keep.x, keep.y)
                       : make_uint4(keep.x, keep.y, recv.x, recv.y);
#pragma unroll
            for (int dg = 0; dg < 2; ++dg) {
                bf16x8 av = *(const bf16x8*)(Vs2 + ((tt * 2 + hi) * 64 + dg * 32 + l31) * 8);
                acc[dg] = __builtin_amdgcn_mfma_f32_32x32x16_bf16(av, fr.b8, acc[dg], 0, 0, 0);
            }
        }
    }

    // ---- epilogue: O^T/l -> Ob[b][q][h*64+d] ----
    rs += __shfl_xor(rs, 32);
    float rinv = 1.0f / rs;
    bf16_t* obase = Ob + (size_t)(b * SEQ + q) * DIM + h * HD;
#pragma unroll
    for (int dg = 0; dg < 2; ++dg)
#pragma unroll
        for (int g2 = 0; g2 < 4; ++g2) {
            bf16x4 o;
#pragma unroll
            for (int jl = 0; jl < 4; ++jl) o[jl] = (bf16_t)(acc[dg][4 * g2 + jl] * rinv);
            *(bf16x4*)(obase + 32 * dg + 8 * g2 + 4 * hi) = o;
        }
}

// ======================= launcher =======================
extern "C" void kernel_launch(void* const* d_in, const int* in_sizes, int n_in,
                              void* d_out, int out_size, void* d_ws, size_t ws_size,
                              hipStream_t stream) {
    const float* x    = (const float*)d_in[0];
    const float* fcos = (const float*)d_in[2];
    const float* fsin = (const float*)d_in[3];
    const float* wq   = (const float*)d_in[5];
    const float* wk   = (const float*)d_in[6];
    const float* wv   = (const float*)d_in[7];
    const float* wo   = (const float*)d_in[8];
    float* out = (float*)d_out;

    char* ws = (char*)d_ws;
    bf16_t* Xb    = (bf16_t*)(ws + 0);            //  8 MB  [4096][1024]
    bf16_t* Attnb = Xb;                           // alias (Xb dead after gemm_qkv)
    bf16_t* WqkvT = (bf16_t*)(ws + 8388608);      //  3 MB  [1536][1024]
    bf16_t* WoT   = (bf16_t*)(ws + 11534336);     //  2 MB  [1024][1024]
    bf16_t* Qb    = (bf16_t*)(ws + 13631488);     //  8 MB  [B][16][S][64]
    bf16_t* Kb    = (bf16_t*)(ws + 22020096);     //  2 MB  [B][4][32 tiles][4096]
    bf16_t* Vt    = (bf16_t*)(ws + 24117248);     //  2 MB  [B][4][32 tiles][4096]
    // total 26,214,400 B

    cast_x_kernel<<<ROWS * DIM / 1024, 256, 0, stream>>>(x, Xb);
    transpose_w_all<<<640, 256, 0, stream>>>(wq, wk, wv, wo, WqkvT, WoT);

    gemm_qkv_kernel<<<dim3(QKVN / 128, ROWS / 128), 256, 0, stream>>>(Xb, WqkvT, fcos, fsin, Qb, Kb, Vt);

    attn_kernel<<<512, 256, 0, stream>>>(Qb, Kb, Vt, Attnb);

    gemm_bt_kernel<<<dim3(DIM / 128, ROWS / 128), 256, 0, stream>>>(Attnb, WoT, out, ROWS, DIM, DIM);
}

// Round 6
// 202.362 us; speedup vs baseline: 1.0458x; 1.0267x over previous
//
#include <hip/hip_runtime.h>

typedef __bf16 bf16_t;
typedef __bf16 bf16x8 __attribute__((ext_vector_type(8)));
typedef __bf16 bf16x4 __attribute__((ext_vector_type(4)));
typedef float f32x4 __attribute__((ext_vector_type(4)));
typedef float f32x16 __attribute__((ext_vector_type(16)));

#if __has_builtin(__builtin_amdgcn_exp2f)
#define EXP2F __builtin_amdgcn_exp2f
#else
#define EXP2F exp2f
#endif

// ---------------- constants (problem shape is fixed) ----------------
#define BATCH 2
#define SEQ   2048
#define DIM   1024
#define NQH   16
#define NKVH  4
#define HD    64
#define ROWS  (BATCH*SEQ)      // 4096
#define QKVN  1536             // 1024 q + 256 k + 256 v
#define QSCALE 0.1803368801111f   // 0.125 * log2(e), folded into Q at projection

// async global->LDS DMA, 16B per lane, LDS dest = wave-uniform base + lane*16
static __device__ __forceinline__ void gld16(const bf16_t* g, bf16_t* l) {
    __builtin_amdgcn_global_load_lds((const __attribute__((address_space(1))) void*)g,
                                     (__attribute__((address_space(3))) void*)l,
                                     16, 0, 0);
}

// ======================= cast x -> bf16 =======================
__global__ __launch_bounds__(256) void cast_x_kernel(const float* __restrict__ x,
                                                     bf16_t* __restrict__ o) {
    size_t i = ((size_t)blockIdx.x * 256 + threadIdx.x) * 4;
    float4 v = *(const float4*)(x + i);
    bf16x4 r;
    r[0] = (bf16_t)v.x; r[1] = (bf16_t)v.y; r[2] = (bf16_t)v.z; r[3] = (bf16_t)v.w;
    *(bf16x4*)(o + i) = r;
}

// ============ all 4 weight transposes in ONE dispatch ============
__global__ __launch_bounds__(256) void transpose_w_all(const float* __restrict__ wq,
                                                       const float* __restrict__ wk,
                                                       const float* __restrict__ wv,
                                                       const float* __restrict__ wo,
                                                       bf16_t* __restrict__ WqkvT,
                                                       bf16_t* __restrict__ WoT) {
    int bid = blockIdx.x;          // 0..639
    const float* src; bf16_t* dst; int N, nt, kt2;
    if (bid < 256)      { src = wq; dst = WqkvT;                      N = 1024; int i = bid;       nt = i & 15; kt2 = i >> 4; }
    else if (bid < 320) { src = wk; dst = WqkvT + (size_t)1024*1024;  N = 256;  int i = bid - 256; nt = i & 3;  kt2 = i >> 2; }
    else if (bid < 384) { src = wv; dst = WqkvT + (size_t)1280*1024;  N = 256;  int i = bid - 320; nt = i & 3;  kt2 = i >> 2; }
    else                { src = wo; dst = WoT;                        N = 1024; int i = bid - 384; nt = i & 15; kt2 = i >> 4; }

    __shared__ float tile[64][65];
    int t = threadIdx.x;
    {
        int r = t >> 2, cb = (t & 3) * 16;
        const float* s = src + (size_t)(kt2 * 64 + r) * N + nt * 64 + cb;
#pragma unroll
        for (int j = 0; j < 16; j += 4) {
            float4 v = *(const float4*)(s + j);
            tile[r][cb + j + 0] = v.x; tile[r][cb + j + 1] = v.y;
            tile[r][cb + j + 2] = v.z; tile[r][cb + j + 3] = v.w;
        }
    }
    __syncthreads();
    {
        int n = t >> 2, kb = (t & 3) * 16;
        union { bf16_t h[16]; uint4 u[2]; } pk;
#pragma unroll
        for (int j = 0; j < 16; ++j) pk.h[j] = (bf16_t)tile[kb + j][n];
        bf16_t* d = dst + (size_t)(nt * 64 + n) * 1024 + kt2 * 64 + kb;
        ((uint4*)d)[0] = pk.u[0];
        ((uint4*)d)[1] = pk.u[1];
    }
}

// ======================= GEMM1: x @ Wqkv^T with fused RoPE + layout epilogue =======================
// K layout out: Kb[b][kv][kt][d>>3][key&63][d&7]   (tile-contiguous, 4096 elem/tile)
// V layout out: Vt[b][kv][kt][key>>3 (local)][d][key&7] (tile-contiguous)
__global__ __launch_bounds__(256, 2) void gemm_qkv_kernel(const bf16_t* __restrict__ A,
                                                          const bf16_t* __restrict__ Bt,
                                                          const float* __restrict__ fcos,
                                                          const float* __restrict__ fsin,
                                                          bf16_t* __restrict__ Qb,
                                                          bf16_t* __restrict__ Kb,
                                                          bf16_t* __restrict__ Vt) {
    const int K = 1024;
    __shared__ __align__(16) bf16_t As[128 * 32];
    __shared__ __align__(16) bf16_t Bs[128 * 32];
    int t = threadIdx.x;
    int w = t >> 6, L = t & 63, quad = L >> 4, l15 = L & 15;
    int wr = (w >> 1) * 64, wc = (w & 1) * 64;
    int bnb = blockIdx.x;                 // 0..11
    int bn = bnb * 128, bm = blockIdx.y * 128;

    const bf16_t* Ag0 = A  + (size_t)(bm + w * 32 + (L >> 2)) * K + (L & 3) * 8;
    const bf16_t* Ag1 = Ag0 + (size_t)16 * K;
    const bf16_t* Bg0 = Bt + (size_t)(bn + w * 32 + (L >> 2)) * K + (L & 3) * 8;
    const bf16_t* Bg1 = Bg0 + (size_t)16 * K;
    bf16_t* Al = As + w * 1024;
    bf16_t* Bl = Bs + w * 1024;

    f32x4 acc[4][4] = {};

    for (int k0 = 0; k0 < K; k0 += 32) {
        __syncthreads();
        gld16(Ag0 + k0, Al);
        gld16(Ag1 + k0, Al + 512);
        gld16(Bg0 + k0, Bl);
        gld16(Bg1 + k0, Bl + 512);
        __syncthreads();

        bf16x8 a[4], b[4];
#pragma unroll
        for (int i = 0; i < 4; ++i) {
            a[i] = ((const bf16x8*)As)[(wr + 16 * i + l15) * 4 + quad];
            b[i] = ((const bf16x8*)Bs)[(wc + 16 * i + l15) * 4 + quad];
        }
#pragma unroll
        for (int i = 0; i < 4; ++i)
#pragma unroll
            for (int j = 0; j < 4; ++j)
                acc[i][j] = __builtin_amdgcn_mfma_f32_16x16x32_bf16(a[i], b[j], acc[i][j], 0, 0, 0);
    }

    // ---- fused epilogue ----
    int region = (bnb >= 10) ? 2 : (bnb >= 8) ? 1 : 0;
#pragma unroll
    for (int i = 0; i < 4; ++i) {
        int row0 = bm + wr + 16 * i + quad * 4;
        int b = row0 >> 11, s0 = row0 & 2047;
#pragma unroll
        for (int j = 0; j < 4; ++j) {
            int col = bn + wc + 16 * j + l15;
            if (region == 2) {                      // V: tile-contiguous permuted layout
                int kvh = (col >> 6) - 20, d = col & 63;
                int kt = s0 >> 6, kl = s0 & 63;
                bf16x4 o;
#pragma unroll
                for (int r = 0; r < 4; ++r) o[r] = (bf16_t)acc[i][j][r];
                *(bf16x4*)(Vt + ((size_t)((b * NKVH + kvh) * 32 + kt)) * 4096
                              + ((kl >> 3) * 64 + d) * 8 + (kl & 7)) = o;
            } else {                                // Q or K: RoPE
                int d = col & 63, fi = d >> 1;
                int odd = col & 1;
#pragma unroll
                for (int r = 0; r < 4; ++r) {
                    int s = s0 + r;
                    float v = acc[i][j][r];
                    float p = __shfl_xor(v, 1);
                    float c = fcos[s * 32 + fi], sn = fsin[s * 32 + fi];
                    float o = odd ? (p * sn + v * c) : (v * c - p * sn);
                    if (region == 0) {
                        int h = col >> 6;
                        Qb[((size_t)((b * NQH + h) * SEQ + s)) * HD + d] = (bf16_t)(o * QSCALE);
                    } else {                        // K: tile-contiguous [d>>3][key][d&7]
                        int kvh = (col >> 6) - 16;
                        int kt = s >> 6, kl = s & 63;
                        Kb[((size_t)((b * NKVH + kvh) * 32 + kt)) * 4096
                           + ((d >> 3) * 64 + kl) * 8 + (d & 7)] = (bf16_t)o;
                    }
                }
            }
        }
    }
}

// ======================= GEMM2: attn @ Wo^T, fp32 out =======================
__global__ __launch_bounds__(256, 2) void gemm_bt_kernel(const bf16_t* __restrict__ A,
                                                         const bf16_t* __restrict__ Bt,
                                                         float* __restrict__ C,
                                                         int M, int N, int K) {
    __shared__ __align__(16) bf16_t As[128 * 32];
    __shared__ __align__(16) bf16_t Bs[128 * 32];
    int t = threadIdx.x;
    int w = t >> 6, L = t & 63, quad = L >> 4, l15 = L & 15;
    int wr = (w >> 1) * 64, wc = (w & 1) * 64;
    int bn = blockIdx.x * 128, bm = blockIdx.y * 128;

    const bf16_t* Ag0 = A  + (size_t)(bm + w * 32 + (L >> 2)) * K + (L & 3) * 8;
    const bf16_t* Ag1 = Ag0 + (size_t)16 * K;
    const bf16_t* Bg0 = Bt + (size_t)(bn + w * 32 + (L >> 2)) * K + (L & 3) * 8;
    const bf16_t* Bg1 = Bg0 + (size_t)16 * K;
    bf16_t* Al = As + w * 1024;
    bf16_t* Bl = Bs + w * 1024;

    f32x4 acc[4][4] = {};

    for (int k0 = 0; k0 < K; k0 += 32) {
        __syncthreads();
        gld16(Ag0 + k0, Al);
        gld16(Ag1 + k0, Al + 512);
        gld16(Bg0 + k0, Bl);
        gld16(Bg1 + k0, Bl + 512);
        __syncthreads();

        bf16x8 a[4], b[4];
#pragma unroll
        for (int i = 0; i < 4; ++i) {
            a[i] = ((const bf16x8*)As)[(wr + 16 * i + l15) * 4 + quad];
            b[i] = ((const bf16x8*)Bs)[(wc + 16 * i + l15) * 4 + quad];
        }
#pragma unroll
        for (int i = 0; i < 4; ++i)
#pragma unroll
            for (int j = 0; j < 4; ++j)
                acc[i][j] = __builtin_amdgcn_mfma_f32_16x16x32_bf16(a[i], b[j], acc[i][j], 0, 0, 0);
    }

#pragma unroll
    for (int i = 0; i < 4; ++i) {
        int row = bm + wr + 16 * i + quad * 4;
#pragma unroll
        for (int j = 0; j < 4; ++j) {
            int col = bn + wc + 16 * j + l15;
            float* cp = C + (size_t)row * N + col;
#pragma unroll
            for (int r = 0; r < 4; ++r)
                cp[(size_t)r * N] = acc[i][j][r];
        }
    }
}

// ======================= flash attention v6: barrier-free waves, 32x32x16 MFMA =======================
// Per-wave math identical to verified v5; scheduling rebuilt:
//  - block (256 thr) = one 64-row q-tile 'a' (0..31) of one (b,h); 4 independent waves:
//      wave w: rowg=w&1 (rows 64a+32*rowg..+31), parity=w>>1 (key-tiles kt=parity,parity+2,..<=a)
//  - NO staging, NO per-iter barriers: K/V fragments read straight from global
//    (tile-contiguous layouts -> every read is a coalesced b128; tiles live in L2/L1)
//  - no-max softmax partials are additive: parity 0/1 waves merge (O^T, rs) via one
//    end-of-kernel LDS exchange (single __syncthreads in whole kernel)
//  - 1024 blocks = 4/CU = 16 waves/CU; sizes {j+1,16-j,17+j,32-j} share an XCD slot
__global__ __launch_bounds__(256, 4) void attn_kernel(const bf16_t* __restrict__ Qb,
                                                      const bf16_t* __restrict__ Kb,
                                                      const bf16_t* __restrict__ Vt,
                                                      bf16_t* __restrict__ Ob) {
    int u = blockIdx.x;
    int k4 = u >> 8, x = u & 255;
    int j = x >> 5, bh = x & 31, b = bh >> 4, h = bh & 15;
    int a = (k4 == 0) ? j : (k4 == 1) ? (15 - j) : (k4 == 2) ? (16 + j) : (31 - j);
    int kv = h >> 2;
    int t = threadIdx.x, w = t >> 6, lane = t & 63, hi = lane >> 5, l31 = lane & 31;
    int rowg = w & 1, parity = w >> 1;
    int q = 64 * a + 32 * rowg + l31;

    __shared__ float cO[2][32][64];     // combine buffer: [rowg][dg*16+r][lane]
    __shared__ float cRS[2][32];

    const bf16_t* Ktile = Kb + ((size_t)((b * NKVH + kv) * 32)) * 4096;
    const bf16_t* Vtile = Vt + ((size_t)((b * NKVH + kv) * 32)) * 4096;
    const bf16_t* Qrow  = Qb + ((size_t)((b * NQH + h) * SEQ + q)) * HD;

    // Q fragments: B[n=q=l31][k=d=16ks+8hi+j]
    bf16x8 qf[4];
#pragma unroll
    for (int ks = 0; ks < 4; ++ks)
        qf[ks] = *(const bf16x8*)(Qrow + ks * 16 + hi * 8);

    f32x16 acc[2] = {};      // O^T: d-tiles dg=0,1
    float rs = 0.f;

    for (int kt = parity; kt <= a; kt += 2) {
        const bf16_t* Kt = Ktile + (size_t)kt * 4096;
        const bf16_t* Vv = Vtile + (size_t)kt * 4096;

        // ---- S^T: 2 key-groups x 4 d-slices (K A-frags direct from global) ----
        f32x16 st[2];
#pragma unroll
        for (int kg = 0; kg < 2; ++kg) {
            f32x16 z = {};
#pragma unroll
            for (int ks = 0; ks < 4; ++ks) {
                bf16x8 ak = *(const bf16x8*)(Kt + ((ks * 2 + hi) * 64 + kg * 32 + l31) * 8);
                z = __builtin_amdgcn_mfma_f32_32x32x16_bf16(ak, qf[ks], z, 0, 0, 0);
            }
            st[kg] = z;
        }

        // ---- P = exp2(S^T) (+ diagonal mask), pack into bf16x4 groups ----
        bool diag = (kt == a);
        uint2 pk[2][2][2];
#pragma unroll
        for (int c = 0; c < 2; ++c)
#pragma unroll
            for (int uu = 0; uu < 2; ++uu)
#pragma unroll
                for (int hh = 0; hh < 2; ++hh) {
                    bf16x4 g;
#pragma unroll
                    for (int jl = 0; jl < 4; ++jl) {
                        int r = 8 * uu + 4 * hh + jl;
                        float p = EXP2F(st[c][r]);
                        if (diag) {
                            int key = kt * 64 + 32 * c + 16 * uu + 8 * hh + 4 * hi + jl;
                            if (key > q) p = 0.f;
                        }
                        rs += p;
                        g[jl] = (bf16_t)p;
                    }
                    union { bf16x4 b4; uint2 u2; } cv; cv.b4 = g;
                    pk[c][uu][hh] = cv.u2;
                }

        // ---- O^T += V^T · P^T : 4 key-slices x 2 d-groups (V A-frags from global) ----
#pragma unroll
        for (int tt = 0; tt < 4; ++tt) {
            int uu = tt & 1, c = tt >> 1;
            uint2 keep = hi ? pk[c][uu][1] : pk[c][uu][0];
            uint2 send = hi ? pk[c][uu][0] : pk[c][uu][1];
            uint2 recv;
            recv.x = __shfl_xor(send.x, 32);
            recv.y = __shfl_xor(send.y, 32);
            union { uint4 u4; bf16x8 b8; } fr;
            fr.u4 = hi ? make_uint4(recv.x, recv.y, keep.x, keep.y)
                       : make_uint4(keep.x, keep.y, recv.x, recv.y);
#pragma unroll
            for (int dg = 0; dg < 2; ++dg) {
                bf16x8 av = *(const bf16x8*)(Vv + ((tt * 2 + hi) * 64 + dg * 32 + l31) * 8);
                acc[dg] = __builtin_amdgcn_mfma_f32_32x32x16_bf16(av, fr.b8, acc[dg], 0, 0, 0);
            }
        }
    }

    // ---- reduce rs across hi halves (per wave) ----
    rs += __shfl_xor(rs, 32);

    // ---- merge parity partners through LDS (additive: no-max softmax) ----
    if (parity == 1) {
#pragma unroll
        for (int dg = 0; dg < 2; ++dg)
#pragma unroll
            for (int r = 0; r < 16; ++r)
                cO[rowg][dg * 16 + r][lane] = acc[dg][r];
        if (hi == 0) cRS[rowg][l31] = rs;
    }
    __syncthreads();
    if (parity == 0) {
#pragma unroll
        for (int dg = 0; dg < 2; ++dg)
#pragma unroll
            for (int r = 0; r < 16; ++r)
                acc[dg][r] += cO[rowg][dg * 16 + r][lane];
        rs += cRS[rowg][l31];

        float rinv = 1.0f / rs;
        bf16_t* obase = Ob + (size_t)(b * SEQ + q) * DIM + h * HD;
#pragma unroll
        for (int dg = 0; dg < 2; ++dg)
#pragma unroll
            for (int g2 = 0; g2 < 4; ++g2) {
                bf16x4 o;
#pragma unroll
                for (int jl = 0; jl < 4; ++jl) o[jl] = (bf16_t)(acc[dg][4 * g2 + jl] * rinv);
                *(bf16x4*)(obase + 32 * dg + 8 * g2 + 4 * hi) = o;
            }
    }
}

// ======================= launcher =======================
extern "C" void kernel_launch(void* const* d_in, const int* in_sizes, int n_in,
                              void* d_out, int out_size, void* d_ws, size_t ws_size,
                              hipStream_t stream) {
    const float* x    = (const float*)d_in[0];
    const float* fcos = (const float*)d_in[2];
    const float* fsin = (const float*)d_in[3];
    const float* wq   = (const float*)d_in[5];
    const float* wk   = (const float*)d_in[6];
    const float* wv   = (const float*)d_in[7];
    const float* wo   = (const float*)d_in[8];
    float* out = (float*)d_out;

    char* ws = (char*)d_ws;
    bf16_t* Xb    = (bf16_t*)(ws + 0);            //  8 MB  [4096][1024]
    bf16_t* Attnb = Xb;                           // alias (Xb dead after gemm_qkv)
    bf16_t* WqkvT = (bf16_t*)(ws + 8388608);      //  3 MB  [1536][1024]
    bf16_t* WoT   = (bf16_t*)(ws + 11534336);     //  2 MB  [1024][1024]
    bf16_t* Qb    = (bf16_t*)(ws + 13631488);     //  8 MB  [B][16][S][64]
    bf16_t* Kb    = (bf16_t*)(ws + 22020096);     //  2 MB  [B][4][32 tiles][4096]
    bf16_t* Vt    = (bf16_t*)(ws + 24117248);     //  2 MB  [B][4][32 tiles][4096]
    // total 26,214,400 B

    cast_x_kernel<<<ROWS * DIM / 1024, 256, 0, stream>>>(x, Xb);
    transpose_w_all<<<640, 256, 0, stream>>>(wq, wk, wv, wo, WqkvT, WoT);

    gemm_qkv_kernel<<<dim3(QKVN / 128, ROWS / 128), 256, 0, stream>>>(Xb, WqkvT, fcos, fsin, Qb, Kb, Vt);

    attn_kernel<<<1024, 256, 0, stream>>>(Qb, Kb, Vt, Attnb);

    gemm_bt_kernel<<<dim3(DIM / 128, ROWS / 128), 256, 0, stream>>>(Attnb, WoT, out, ROWS, DIM, DIM);
}